// Round 7
// baseline (51.487 us; speedup 1.0000x reference)
//
#include <hip/hip_runtime.h>
#include <hip/hip_bf16.h>
#include <math.h>

typedef short bf16x8 __attribute__((ext_vector_type(8)));
typedef float f32x4  __attribute__((ext_vector_type(4)));

static __device__ __forceinline__ unsigned short f2bf(float x) {
    unsigned u = __builtin_bit_cast(unsigned, x);
    return (unsigned short)((u + 0x7fffu + ((u >> 16) & 1u)) >> 16);
}

static __device__ __forceinline__ bf16x8 pack8(float4 u0, float4 u1) {
    bf16x8 f;
    f[0] = (short)f2bf(u0.x); f[1] = (short)f2bf(u0.y);
    f[2] = (short)f2bf(u0.z); f[3] = (short)f2bf(u0.w);
    f[4] = (short)f2bf(u1.x); f[5] = (short)f2bf(u1.y);
    f[6] = (short)f2bf(u1.z); f[7] = (short)f2bf(u1.w);
    return f;
}

static __device__ __forceinline__ void async_cp16(const void* gsrc, void* ldsdst) {
    __builtin_amdgcn_global_load_lds(
        (const __attribute__((address_space(1))) void*)gsrc,
        (__attribute__((address_space(3))) void*)ldsdst, 16, 0, 0);
}

// ---- centroid image + c2 + (block ncb: label-width detect + zero out) -------
// img[cb16][k][lane][j] = cent[cb16*16 + (lane&15)][k*32 + (lane>>4)*8 + j]
__global__ __launch_bounds__(64) void cent_prep_kernel(
    const float* __restrict__ cent, char* __restrict__ Cimg,
    float* __restrict__ c2g, const unsigned* __restrict__ w, int nelem,
    unsigned* __restrict__ flag, float* __restrict__ out, int out_size, int ncb) {
    const int lane = threadIdx.x;
    if ((int)blockIdx.x < ncb) {
        const int cb = blockIdx.x;
        const int r = cb * 16 + (lane & 15);
        const int q = lane >> 4;
        const float4* C4 = (const float4*)cent;
        float s = 0.0f;
        #pragma unroll
        for (int k = 0; k < 8; ++k) {
            int fidx = r * 64 + k * 8 + q * 2;
            float4 u0 = C4[fidx], u1 = C4[fidx + 1];
            *(bf16x8*)(Cimg + ((size_t)(cb * 8 + k) * 64 + lane) * 16) = pack8(u0, u1);
            s += u0.x*u0.x + u0.y*u0.y + u0.z*u0.z + u0.w*u0.w
               + u1.x*u1.x + u1.y*u1.y + u1.z*u1.z + u1.w*u1.w;
        }
        s += __shfl_xor(s, 16, 64);
        s += __shfl_xor(s, 32, 64);
        if (lane < 16) c2g[cb * 16 + lane] = s;
    } else {
        int npairs = nelem / 2; if (npairs > 4096) npairs = 4096;
        unsigned acc = 0;
        for (int i = lane; i < npairs; i += 64) acc |= w[2 * i + 1];
        #pragma unroll
        for (int m = 32; m >= 1; m >>= 1) acc |= __shfl_xor(acc, m, 64);
        if (lane == 0) *flag = (acc != 0u) ? 1u : 0u;   // 1 = int32
        for (int i = lane; i < out_size; i += 64) out[i] = 0.0f;
    }
}

// ---- main: 8 waves = 4 row-groups(32) x 2 col-halves(64). a[2][8] in regs. --
// acc initialized to -(e2_row + c2_col)/2 so d2 = -2*acc_final: epilogue is a
// single max+compare per (m,n). pos computed exactly (fp32) in the prologue
// via a label-centroid gather. B double-buffered in LDS (64KB chunks).
#define CHUNK_BYTES 65536
// LDS: Bb0 @0, Bb1 @65536, c2l @131072 (4KB), red @135168 (64B)
#define MAIN_SMEM 135232

__global__ __launch_bounds__(512) void main4_kernel(
    const float* __restrict__ emb, const float* __restrict__ cent,
    const char* __restrict__ Cimg, const float* __restrict__ c2g,
    const int* __restrict__ labw, const unsigned* __restrict__ flag,
    float* __restrict__ out, int nchunk, float invB) {
    extern __shared__ char smem[];
    char*  Bb0 = smem;
    char*  Bb1 = smem + CHUNK_BYTES;
    float* c2l = (float*)(smem + 131072);
    float* red = (float*)(smem + 135168);

    const int tid = threadIdx.x, lane = tid & 63, wid = tid >> 6;
    const int wr = wid >> 1, wc = wid & 1;      // 4x2 wave grid; tile 32r x 64c
    const int row0 = blockIdx.x * 128;
    const int l15 = lane & 15, q = lane >> 4;

    // stage chunk 0 of the centroid image (async, direct to LDS)
    #pragma unroll
    for (int i = 0; i < 8; ++i)
        async_cp16(Cimg + i * 8192 + tid * 16, Bb0 + i * 8192 + wid * 1024);

    // c2 -> LDS (1024 floats)
    c2l[tid] = c2g[tid];
    c2l[tid + 512] = c2g[tid + 512];

    const int is32 = (*flag != 0u);

    // A: 32 rows/wave -> registers (bf16 fragments); e2, labels, exact pos.
    bf16x8 a[2][8];
    float e2m[2]; int labv[2];
    float fsum = 0.0f;
    #pragma unroll
    for (int m = 0; m < 2; ++m) {
        const int rg = row0 + wr * 32 + m * 16 + l15;
        const int lbl = is32 ? labw[rg] : labw[2 * rg];
        labv[m] = lbl;
        const float4* E4 = (const float4*)emb + (size_t)rg * 64;
        const float4* C4 = (const float4*)cent + (size_t)lbl * 64;
        float s = 0.0f, dot = 0.0f, cc = 0.0f;
        #pragma unroll
        for (int k = 0; k < 8; ++k) {
            float4 u0 = E4[k * 8 + q * 2], u1 = E4[k * 8 + q * 2 + 1];
            a[m][k] = pack8(u0, u1);
            s += u0.x*u0.x + u0.y*u0.y + u0.z*u0.z + u0.w*u0.w
               + u1.x*u1.x + u1.y*u1.y + u1.z*u1.z + u1.w*u1.w;
            float4 v0 = C4[k * 8 + q * 2], v1 = C4[k * 8 + q * 2 + 1];
            dot += u0.x*v0.x + u0.y*v0.y + u0.z*v0.z + u0.w*v0.w
                 + u1.x*v1.x + u1.y*v1.y + u1.z*v1.z + u1.w*v1.w;
            cc += v0.x*v0.x + v0.y*v0.y + v0.z*v0.z + v0.w*v0.w
                + v1.x*v1.x + v1.y*v1.y + v1.z*v1.z + v1.w*v1.w;
        }
        s += __shfl_xor(s, 16, 64);   s += __shfl_xor(s, 32, 64);
        dot += __shfl_xor(dot, 16, 64); dot += __shfl_xor(dot, 32, 64);
        cc += __shfl_xor(cc, 16, 64); cc += __shfl_xor(cc, 32, 64);
        e2m[m] = s;
        if (wc == 0 && lane < 16) {          // one lane per row adds pos = d2
            float d2p = fmaxf(s + cc - 2.0f * dot, 0.0f);
            fsum += d2p;
        }
    }

    // e2 of rows (m, q*4+r), redistributed once
    float er[2][4];
    #pragma unroll
    for (int m = 0; m < 2; ++m)
        #pragma unroll
        for (int r = 0; r < 4; ++r)
            er[m][r] = __shfl(e2m[m], q * 4 + r, 64);

    __syncthreads();   // drains async chunk0 + c2l writes

    for (int ch = 0; ch < nchunk; ++ch) {
        const char* Bcur = (ch & 1) ? Bb1 : Bb0;
        char* Bnxt = (ch & 1) ? Bb0 : Bb1;
        if (ch + 1 < nchunk) {
            const char* src = Cimg + (size_t)(ch + 1) * CHUNK_BYTES;
            #pragma unroll
            for (int i = 0; i < 8; ++i)
                async_cp16(src + i * 8192 + tid * 16, Bnxt + i * 8192 + wid * 1024);
        }

        // acc init: -(e2_row + c2_col)/2  =>  d2 = -2 * acc_final
        float c2v[4];
        #pragma unroll
        for (int n = 0; n < 4; ++n)
            c2v[n] = -0.5f * c2l[ch * 128 + wc * 64 + n * 16 + l15];
        f32x4 acc[2][4];
        #pragma unroll
        for (int m = 0; m < 2; ++m)
            #pragma unroll
            for (int n = 0; n < 4; ++n)
                #pragma unroll
                for (int r = 0; r < 4; ++r)
                    acc[m][n][r] = fmaf(-0.5f, er[m][r], c2v[n]);

        #pragma unroll
        for (int k = 0; k < 8; ++k) {
            const char* Bk = Bcur + (size_t)(wc * 32 + k) * 1024 + lane * 16;
            #pragma unroll
            for (int n = 0; n < 4; ++n) {
                bf16x8 bn = *(const bf16x8*)(Bk + n * 8192);
                acc[0][n] = __builtin_amdgcn_mfma_f32_16x16x32_bf16(a[0][k], bn, acc[0][n], 0, 0, 0);
                acc[1][n] = __builtin_amdgcn_mfma_f32_16x16x32_bf16(a[1][k], bn, acc[1][n], 0, 0, 0);
            }
        }

        // screen: any d2 < 2  <=>  acc > -1
        unsigned need = 0;
        #pragma unroll
        for (int m = 0; m < 2; ++m)
            #pragma unroll
            for (int n = 0; n < 4; ++n) {
                float mx = fmaxf(fmaxf(acc[m][n][0], acc[m][n][1]),
                                 fmaxf(acc[m][n][2], acc[m][n][3]));
                need |= (unsigned)(mx > -1.0f) << (m * 4 + n);
            }
        if (__any(need != 0)) {   // rare: recompute fired groups exactly
            #pragma unroll
            for (int m = 0; m < 2; ++m)
                #pragma unroll
                for (int n = 0; n < 4; ++n)
                    if ((need >> (m * 4 + n)) & 1u) {
                        int colg = ch * 128 + wc * 64 + n * 16 + l15;
                        #pragma unroll
                        for (int r = 0; r < 4; ++r) {
                            float d2 = fmaxf(-2.0f * acc[m][n][r], 0.0f);
                            int lb = __shfl(labv[m], q * 4 + r, 64);
                            if (d2 < 1.0f && colg != lb) {
                                float t = 1.0f - sqrtf(d2);
                                fsum += t * t;
                            }
                        }
                    }
        }
        asm volatile("s_waitcnt vmcnt(0)" ::: "memory");
        __builtin_amdgcn_s_barrier();
    }

    #pragma unroll
    for (int m = 32; m >= 1; m >>= 1) fsum += __shfl_xor(fsum, m, 64);
    if (lane == 0) red[wid] = fsum;
    __syncthreads();
    if (tid == 0) {
        float t = 0.0f;
        #pragma unroll
        for (int w = 0; w < 8; ++w) t += red[w];
        atomicAdd(out, t * invB);
    }
}

// ======================= fallback (round-1, verified) ========================
#define FB_THREADS 512
#define FB_SMEM 132672
__device__ int g_lab_is64;

__global__ void fb_detect_kernel(const unsigned* __restrict__ w, int nelem,
                                 float* __restrict__ out, int out_size) {
    __shared__ unsigned red[256];
    unsigned acc = 0;
    for (int i = threadIdx.x; i < nelem / 2; i += 256) acc |= w[2 * i + 1];
    red[threadIdx.x] = acc;
    __syncthreads();
    for (int s = 128; s > 0; s >>= 1) {
        if (threadIdx.x < s) red[threadIdx.x] |= red[threadIdx.x + s];
        __syncthreads();
    }
    if (threadIdx.x == 0) g_lab_is64 = (red[0] == 0u) ? 1 : 0;
    for (int i = threadIdx.x; i < out_size; i += 256) out[i] = 0.0f;
}

__global__ __launch_bounds__(FB_THREADS) void fb_loss_kernel(
    const float* __restrict__ emb, const float* __restrict__ cent,
    const int* __restrict__ labw, float* __restrict__ out,
    int nchunk, float invB) {
    extern __shared__ char smem[];
    char* Abf = smem;
    char* Cbf = smem + 65536;
    float* e2 = (float*)(smem + 131072);
    float* c2 = (float*)(smem + 131584);
    int* lab = (int*)(smem + 132096);
    float* red = (float*)(smem + 132608);

    const int tid = threadIdx.x, lane = tid & 63, wid = tid >> 6;
    const int row0 = blockIdx.x * 128;
    const int is64 = g_lab_is64;

    for (int j = 0; j < 16; ++j) {
        int f4 = tid + j * FB_THREADS;
        int r = f4 >> 6, c4 = f4 & 63;
        float4 v = ((const float4*)emb)[(size_t)(row0 + r) * 64 + c4];
        ushort4 h;
        h.x = f2bf(v.x); h.y = f2bf(v.y); h.z = f2bf(v.z); h.w = f2bf(v.w);
        int off = (c4 * 8) ^ ((r & 7) << 4);
        *(ushort4*)(Abf + r * 512 + off) = h;
        float s = v.x*v.x + v.y*v.y + v.z*v.z + v.w*v.w;
        #pragma unroll
        for (int m = 32; m >= 1; m >>= 1) s += __shfl_xor(s, m, 64);
        if (lane == 0) e2[r] = s;
    }
    if (tid < 128) {
        int b = row0 + tid;
        lab[tid] = is64 ? labw[2 * b] : labw[b];
    }
    __syncthreads();

    const int wr = wid >> 1, wc = wid & 1;
    const int l15 = lane & 15, l16 = lane >> 4;
    const int swz = (l15 & 7) << 4;

    float e2v[2][4]; int labv[2][4];
    #pragma unroll
    for (int m = 0; m < 2; ++m)
        #pragma unroll
        for (int r = 0; r < 4; ++r) {
            int rr = wr * 32 + m * 16 + l16 * 4 + r;
            e2v[m][r] = e2[rr]; labv[m][r] = lab[rr];
        }

    float fsum = 0.0f;
    for (int ch = 0; ch < nchunk; ++ch) {
        const float* cbase = cent + (size_t)ch * 128 * 256;
        for (int j = 0; j < 16; ++j) {
            int f4 = tid + j * FB_THREADS;
            int r = f4 >> 6, c4 = f4 & 63;
            float4 v = ((const float4*)cbase)[(size_t)r * 64 + c4];
            ushort4 h;
            h.x = f2bf(v.x); h.y = f2bf(v.y); h.z = f2bf(v.z); h.w = f2bf(v.w);
            int off = (c4 * 8) ^ ((r & 7) << 4);
            *(ushort4*)(Cbf + r * 512 + off) = h;
            float s = v.x*v.x + v.y*v.y + v.z*v.z + v.w*v.w;
            #pragma unroll
            for (int m = 32; m >= 1; m >>= 1) s += __shfl_xor(s, m, 64);
            if (lane == 0) c2[r] = s;
        }
        __syncthreads();

        f32x4 acc[2][4];
        #pragma unroll
        for (int m = 0; m < 2; ++m)
            #pragma unroll
            for (int n = 0; n < 4; ++n) acc[m][n] = (f32x4){0, 0, 0, 0};

        #pragma unroll
        for (int kk = 0; kk < 8; ++kk) {
            int kb = kk * 64 + l16 * 16;
            bf16x8 a[2], b[4];
            #pragma unroll
            for (int m = 0; m < 2; ++m)
                a[m] = *(const bf16x8*)(Abf + (wr * 32 + m * 16 + l15) * 512 + (kb ^ swz));
            #pragma unroll
            for (int n = 0; n < 4; ++n)
                b[n] = *(const bf16x8*)(Cbf + (wc * 64 + n * 16 + l15) * 512 + (kb ^ swz));
            #pragma unroll
            for (int m = 0; m < 2; ++m)
                #pragma unroll
                for (int n = 0; n < 4; ++n)
                    acc[m][n] = __builtin_amdgcn_mfma_f32_16x16x32_bf16(a[m], b[n], acc[m][n], 0, 0, 0);
        }

        float c2v[4]; int colg[4];
        #pragma unroll
        for (int n = 0; n < 4; ++n) {
            int cl = wc * 64 + n * 16 + l15;
            c2v[n] = c2[cl]; colg[n] = ch * 128 + cl;
        }
        unsigned need = 0;
        #pragma unroll
        for (int m = 0; m < 2; ++m)
            #pragma unroll
            for (int n = 0; n < 4; ++n)
                #pragma unroll
                for (int r = 0; r < 4; ++r) {
                    float d2 = fmaf(-2.0f, acc[m][n][r], e2v[m][r] + c2v[n]);
                    d2 = fmaxf(d2, 0.0f);
                    bool isp = (colg[n] == labv[m][r]);
                    fsum += isp ? d2 : 0.0f;
                    need |= (unsigned)((!isp) & (d2 < 1.0f)) << (m * 16 + n * 4 + r);
                }
        if (__any(need != 0)) {
            #pragma unroll
            for (int m = 0; m < 2; ++m)
                #pragma unroll
                for (int n = 0; n < 4; ++n)
                    #pragma unroll
                    for (int r = 0; r < 4; ++r)
                        if ((need >> (m * 16 + n * 4 + r)) & 1u) {
                            float d2 = fmaf(-2.0f, acc[m][n][r], e2v[m][r] + c2v[n]);
                            d2 = fmaxf(d2, 0.0f);
                            float t = 1.0f - sqrtf(d2);
                            fsum += t * t;
                        }
        }
        __syncthreads();
    }
    #pragma unroll
    for (int m = 32; m >= 1; m >>= 1) fsum += __shfl_xor(fsum, m, 64);
    if (lane == 0) red[wid] = fsum;
    __syncthreads();
    if (tid == 0) {
        float t = 0.0f;
        #pragma unroll
        for (int w = 0; w < 8; ++w) t += red[w];
        atomicAdd(out, t * invB);
    }
}

// =============================================================================
extern "C" void kernel_launch(void* const* d_in, const int* in_sizes, int n_in,
                              void* d_out, int out_size, void* d_ws, size_t ws_size,
                              hipStream_t stream) {
    const float* emb = (const float*)d_in[0];
    const float* cent = (const float*)d_in[1];
    const int* labw = (const int*)d_in[2];
    float* out = (float*)d_out;

    const int B = in_sizes[0] / 256;
    const int K = in_sizes[1] / 256;
    const int nchunk = K / 128;
    const float invB = 1.0f / (float)B;

    char* ws = (char*)d_ws;
    const size_t off_flag = 0;
    const size_t off_c2 = 256;
    const size_t off_cimg = 8192;
    const size_t req = off_cimg + (size_t)K * 512;

    if (ws_size >= req) {
        const int ncb = K / 16;               // 64 centroid-image blocks
        cent_prep_kernel<<<ncb + 1, 64, 0, stream>>>(
            cent, ws + off_cimg, (float*)(ws + off_c2),
            (const unsigned*)d_in[2], in_sizes[2], (unsigned*)(ws + off_flag),
            out, out_size, ncb);

        hipFuncSetAttribute(reinterpret_cast<const void*>(main4_kernel),
                            hipFuncAttributeMaxDynamicSharedMemorySize, MAIN_SMEM);
        main4_kernel<<<B / 128, 512, MAIN_SMEM, stream>>>(
            emb, cent, ws + off_cimg, (const float*)(ws + off_c2), labw,
            (const unsigned*)(ws + off_flag), out, nchunk, invB);
    } else {
        fb_detect_kernel<<<1, 256, 0, stream>>>((const unsigned*)d_in[2], in_sizes[2],
                                                out, out_size);
        hipFuncSetAttribute(reinterpret_cast<const void*>(fb_loss_kernel),
                            hipFuncAttributeMaxDynamicSharedMemorySize, FB_SMEM);
        fb_loss_kernel<<<B / 128, FB_THREADS, FB_SMEM, stream>>>(
            emb, cent, labw, out, nchunk, invB);
    }
}